// Round 9
// baseline (119.732 us; speedup 1.0000x reference)
//
#include <hip/hip_runtime.h>

typedef float f32x2 __attribute__((ext_vector_type(2)));
typedef float f32x4 __attribute__((ext_vector_type(4)));
typedef short bf16x8 __attribute__((ext_vector_type(8)));
typedef _Float16 h16x2 __attribute__((ext_vector_type(2)));
typedef _Float16 h16x8 __attribute__((ext_vector_type(8)));

#define LL 512
#define M_ROWS 2048            // 4 * 512
#define KC 768                 // split-K: [hi|hi|lo] x [hi|lo|hi]

#if __has_builtin(__builtin_amdgcn_exp2f)
#define EXP2F __builtin_amdgcn_exp2f
#else
#define EXP2F exp2f
#endif
#define LOG2E 1.44269504088896340736f

__device__ __forceinline__ float quad_swap1(float x) {
    return __int_as_float(__builtin_amdgcn_mov_dpp(__float_as_int(x), 0xB1, 0xF, 0xF, true));
}
__device__ __forceinline__ float quad_swap2(float x) {
    return __int_as_float(__builtin_amdgcn_mov_dpp(__float_as_int(x), 0x4E, 0xF, 0xF, true));
}

__device__ __forceinline__ float fdot2f(h16x2 a, h16x2 b, float c) {
#if __has_builtin(__builtin_amdgcn_fdot2)
    return __builtin_amdgcn_fdot2(a, b, c, false);
#else
    return fmaf((float)a.x, (float)b.x, fmaf((float)a.y, (float)b.y, c));
#endif
}

__device__ __forceinline__ unsigned short bf16_rtne(float x) {
    unsigned u = __float_as_uint(x);
    return (unsigned short)((u + 0x7fffu + ((u >> 16) & 1u)) >> 16);
}
__device__ __forceinline__ float bf16_to_f(unsigned short h) {
    return __uint_as_float((unsigned)h << 16);
}

// ---------------------------------------------------------------------------
// Kernel 0: split fp32 -> bf16 (hi, lo) concatenated along K. (unchanged)
// ---------------------------------------------------------------------------
__global__ __launch_bounds__(64) void split_bf16(
    const float* __restrict__ X, const float* __restrict__ Wq,
    const float* __restrict__ Wk, const float* __restrict__ Wv,
    unsigned short* __restrict__ Xc, unsigned short* __restrict__ Wc)
{
    const int row = blockIdx.x;
    const int t = threadIdx.x;
    const float* src;
    unsigned short* hi1; unsigned short* hi2; unsigned short* lo1;
    if (row < M_ROWS) {
        src = X + (size_t)row * 256;
        hi1 = Xc + (size_t)row * KC;
        hi2 = hi1 + 256;
        lo1 = hi1 + 512;
    } else {
        const int n = row - M_ROWS;          // 0..767
        const int mat = n >> 8, c = n & 255;
        const int srow = (mat == 2) ? (((c & 31) << 3) | (c >> 5)) : c;
        src = (mat == 0 ? Wq : (mat == 1 ? Wk : Wv)) + (size_t)srow * 256;
        hi1 = Wc + (size_t)n * KC;
        lo1 = hi1 + 256;
        hi2 = hi1 + 512;
    }
    const f32x4 v = *(const f32x4*)(src + t * 4);
    ushort4 h, l;
    h.x = bf16_rtne(v.x); h.y = bf16_rtne(v.y); h.z = bf16_rtne(v.z); h.w = bf16_rtne(v.w);
    l.x = bf16_rtne(v.x - bf16_to_f(h.x));
    l.y = bf16_rtne(v.y - bf16_to_f(h.y));
    l.z = bf16_rtne(v.z - bf16_to_f(h.z));
    l.w = bf16_rtne(v.w - bf16_to_f(h.w));
    *(ushort4*)(hi1 + t * 4) = h;
    *(ushort4*)(hi2 + t * 4) = h;
    *(ushort4*)(lo1 + t * 4) = l;
}

// ---------------------------------------------------------------------------
// Kernel 1: Q,K (f16 out) and Vt (f32 out) via bf16 MFMA split-K GEMM.
// (unchanged from R8)
// ---------------------------------------------------------------------------
__global__ __launch_bounds__(64) void qkv_mfma(
    const unsigned short* __restrict__ Xc, const unsigned short* __restrict__ Wc,
    _Float16* __restrict__ Qh, _Float16* __restrict__ Kh, float* __restrict__ Vt)
{
    const int bid = blockIdx.x;
    const int m0 = (bid & 31) * 64;
    const int n0 = (bid >> 5) * 64;
    const int l = threadIdx.x;
    const int lr = l & 15;
    const int lk = (l >> 4) * 8;

    size_t aoff[4], boff[4];
#pragma unroll
    for (int i = 0; i < 4; ++i) {
        aoff[i] = (size_t)(m0 + i * 16 + lr) * KC + lk;
        boff[i] = (size_t)(n0 + i * 16 + lr) * KC + lk;
    }

    f32x4 acc[4][4];
#pragma unroll
    for (int i = 0; i < 4; ++i)
#pragma unroll
        for (int j = 0; j < 4; ++j) acc[i][j] = (f32x4){0.f, 0.f, 0.f, 0.f};

    bf16x8 A0[4], B0[4], A1[4], B1[4];
#pragma unroll
    for (int i = 0; i < 4; ++i) {
        A0[i] = *(const bf16x8*)(Xc + aoff[i]);
        B0[i] = *(const bf16x8*)(Wc + boff[i]);
    }

#pragma unroll 1
    for (int it = 0; it < 24; it += 2) {
        const int ks1 = (it + 1) * 32;
#pragma unroll
        for (int i = 0; i < 4; ++i) {
            A1[i] = *(const bf16x8*)(Xc + aoff[i] + ks1);
            B1[i] = *(const bf16x8*)(Wc + boff[i] + ks1);
        }
#pragma unroll
        for (int ai = 0; ai < 4; ++ai)
#pragma unroll
            for (int bi = 0; bi < 4; ++bi)
                acc[ai][bi] = __builtin_amdgcn_mfma_f32_16x16x32_bf16(
                    A0[ai], B0[bi], acc[ai][bi], 0, 0, 0);
        if (it + 2 < 24) {
            const int ks2 = (it + 2) * 32;
#pragma unroll
            for (int i = 0; i < 4; ++i) {
                A0[i] = *(const bf16x8*)(Xc + aoff[i] + ks2);
                B0[i] = *(const bf16x8*)(Wc + boff[i] + ks2);
            }
        }
#pragma unroll
        for (int ai = 0; ai < 4; ++ai)
#pragma unroll
            for (int bi = 0; bi < 4; ++bi)
                acc[ai][bi] = __builtin_amdgcn_mfma_f32_16x16x32_bf16(
                    A1[ai], B1[bi], acc[ai][bi], 0, 0, 0);
    }

    const int mat = n0 >> 8;
    if (mat == 2) {
#pragma unroll
        for (int ai = 0; ai < 4; ++ai)
#pragma unroll
            for (int bi = 0; bi < 4; ++bi) {
                const int col = (n0 & 255) + bi * 16 + lr;
#pragma unroll
                for (int r = 0; r < 4; ++r) {
                    const int row = m0 + ai * 16 + (l >> 4) * 4 + r;
                    Vt[(size_t)row * 256 + col] = acc[ai][bi][r];
                }
            }
    } else {
        _Float16* Hb = (mat == 0) ? Qh : Kh;
#pragma unroll
        for (int ai = 0; ai < 4; ++ai)
#pragma unroll
            for (int bi = 0; bi < 4; ++bi) {
                const int col = (n0 & 255) + bi * 16 + lr;
#pragma unroll
                for (int r = 0; r < 4; ++r) {
                    const int row = m0 + ai * 16 + (l >> 4) * 4 + r;
                    Hb[(size_t)row * 256 + col] = (_Float16)acc[ai][bi][r];
                }
            }
    }
}

// ---------------------------------------------------------------------------
// Kernel 2: fused grouped-MLP attention — f16 score path, prefetch depth 2.
// grid 512 = 4 batches x 128 q-tiles (4 q rows), 512 threads, 2 blocks/CU.
// thread = (dh = t&3: 8 contiguous d's, g = (t>>2)&7, p = t>>5: k-phase 0..15).
// Pairs of k-steps; each stage's registers are refilled right after their
// consumption -> load-to-use distance ~1.5 compute bodies, zero rotation movs.
// ---------------------------------------------------------------------------
__global__ __launch_bounds__(512, 4) void attn_fused(
    const _Float16* __restrict__ Qh, const _Float16* __restrict__ Kh,
    const float* __restrict__ Vt,
    const float* __restrict__ w_mlp, const float* __restrict__ b_mlp,
    float* __restrict__ out)
{
    const int bid = blockIdx.x;
    const int b = bid & 3;
    const int q0 = (bid >> 2) * 4;

    const int t = threadIdx.x;
    const int dh = t & 3;
    const int p = t >> 5;                    // 0..15
    const int lane32 = t & 31;               // g*4 + dh
    const int g = lane32 >> 2;

    __shared__ float accbuf[16][32][37];     // 75776 B (rows: 4q*8 + l[4])

    const int doff = g * 32 + dh * 8;
    const float bias4 = b_mlp[0] * (LOG2E * 0.25f);

    h16x2 w2[4];
    {
        f32x4 wa = *(const f32x4*)(w_mlp + dh * 8);
        f32x4 wb = *(const f32x4*)(w_mlp + dh * 8 + 4);
        wa *= LOG2E; wb *= LOG2E;
        w2[0] = (h16x2){(_Float16)wa.x, (_Float16)wa.y};
        w2[1] = (h16x2){(_Float16)wa.z, (_Float16)wa.w};
        w2[2] = (h16x2){(_Float16)wb.x, (_Float16)wb.y};
        w2[3] = (h16x2){(_Float16)wb.z, (_Float16)wb.w};
    }

    h16x2 qr2[4][4];
#pragma unroll
    for (int q = 0; q < 4; ++q) {
        const h16x8 qv = *(const h16x8*)(Qh + ((size_t)(b * LL) + q0 + q) * 256 + doff);
        qr2[q][0] = __builtin_shufflevector(qv, qv, 0, 1);
        qr2[q][1] = __builtin_shufflevector(qv, qv, 2, 3);
        qr2[q][2] = __builtin_shufflevector(qv, qv, 4, 5);
        qr2[q][3] = __builtin_shufflevector(qv, qv, 6, 7);
    }

    f32x2 acc2[4][4];
#pragma unroll
    for (int q = 0; q < 4; ++q)
#pragma unroll
        for (int j = 0; j < 4; ++j) acc2[q][j] = (f32x2){0.f, 0.f};
    float l[4] = {0.f, 0.f, 0.f, 0.f};

    const _Float16* kptr = Kh + ((size_t)(b * LL) + p) * 256 + doff;
    const float*    vptr = Vt + ((size_t)(b * LL) + p) * 256 + doff;
    const size_t STR = (size_t)16 * 256;

    const h16x2 zh = {(_Float16)0.f, (_Float16)0.f};

    auto compute = [&](h16x8 kv, f32x4 va, f32x4 vb) {
        h16x2 k2[4] = {__builtin_shufflevector(kv, kv, 0, 1),
                       __builtin_shufflevector(kv, kv, 2, 3),
                       __builtin_shufflevector(kv, kv, 4, 5),
                       __builtin_shufflevector(kv, kv, 6, 7)};
        f32x2 v2[4] = {__builtin_shufflevector(va, va, 0, 1),
                       __builtin_shufflevector(va, va, 2, 3),
                       __builtin_shufflevector(vb, vb, 0, 1),
                       __builtin_shufflevector(vb, vb, 2, 3)};
#pragma unroll
        for (int q = 0; q < 4; ++q) {
            float s = bias4;
#pragma unroll
            for (int j = 0; j < 4; ++j) {
                h16x2 d2 = qr2[q][j] - k2[j];
                h16x2 r2 = __builtin_elementwise_max(d2, zh);
                s = fdot2f(w2[j], r2, s);
            }
            s += quad_swap1(s);
            s += quad_swap2(s);
            s = fmaxf(s, 0.f);
            const float e = EXP2F(s);
            l[q] += e;
            const f32x2 e2 = {e, e};
#pragma unroll
            for (int j = 0; j < 4; ++j)
                acc2[q][j] = __builtin_elementwise_fma(v2[j], e2, acc2[q][j]);
        }
    };

    // ---- pipeline: 2 stages in flight ----
    h16x8 k0 = *(const h16x8*)kptr;
    f32x4 va0 = *(const f32x4*)vptr, vb0 = *(const f32x4*)(vptr + 4);
    h16x8 k1 = *(const h16x8*)(kptr + STR);
    f32x4 va1 = *(const f32x4*)(vptr + STR), vb1 = *(const f32x4*)(vptr + STR + 4);
    kptr += 2 * STR; vptr += 2 * STR;

#pragma unroll 1
    for (int i = 0; i < 16; ++i) {
        compute(k0, va0, vb0);               // consume step 2i
        if (i < 15) {                        // refill stage 0 with step 2i+2
            k0 = *(const h16x8*)kptr;
            va0 = *(const f32x4*)vptr; vb0 = *(const f32x4*)(vptr + 4);
            kptr += STR; vptr += STR;
        }
        compute(k1, va1, vb1);               // consume step 2i+1
        if (i < 15) {                        // refill stage 1 with step 2i+3
            k1 = *(const h16x8*)kptr;
            va1 = *(const f32x4*)vptr; vb1 = *(const f32x4*)(vptr + 4);
            kptr += STR; vptr += STR;
        }
    }

    // ---- epilogue: store 4 q + l, 16-phase LDS reduction, 2 outputs/thread --
    {
        float* rowp = &accbuf[p][lane32][0];
#pragma unroll
        for (int qq = 0; qq < 4; ++qq)
#pragma unroll
            for (int j = 0; j < 4; ++j)
                *(f32x2*)(rowp + qq * 8 + j * 2) = acc2[qq][j];
        if (dh == 0) {
#pragma unroll
            for (int qq = 0; qq < 4; ++qq) accbuf[p][lane32][32 + qq] = l[qq];
        }
    }
    __syncthreads();

    const int c_o = t & 255;
    const int g_o = c_o & 7, d_o = c_o >> 3;
    const int rowb = g_o * 4 + (d_o >> 3);
    const int colb = d_o & 7;
    const int qsel = t >> 8;                 // 0..1
#pragma unroll
    for (int h = 0; h < 2; ++h) {
        const int qh = qsel + 2 * h;         // 0..3
        float s = 0.f, ls = 0.f;
#pragma unroll
        for (int pp = 0; pp < 16; ++pp) {
            s  += accbuf[pp][rowb][qh * 8 + colb];
            ls += accbuf[pp][g_o * 4][32 + qh];
        }
        out[((size_t)(b * LL) + q0 + qh) * 256 + c_o] = s / ls;
    }
}

// ---------------------------------------------------------------------------
extern "C" void kernel_launch(void* const* d_in, const int* in_sizes, int n_in,
                              void* d_out, int out_size, void* d_ws, size_t ws_size,
                              hipStream_t stream) {
    (void)in_sizes; (void)n_in; (void)out_size; (void)ws_size;
    const float* x     = (const float*)d_in[0];
    const float* Wq    = (const float*)d_in[1];
    const float* Wk    = (const float*)d_in[2];
    const float* Wv    = (const float*)d_in[3];
    const float* w_mlp = (const float*)d_in[4];
    const float* b_mlp = (const float*)d_in[5];
    float* outp = (float*)d_out;

    _Float16* Qh = (_Float16*)d_ws;                            // 1 MB
    _Float16* Kh = (_Float16*)((char*)d_ws + (size_t)1048576); // 1 MB
    float*    Vt = (float*)((char*)d_ws + (size_t)2097152);    // 2 MB
    unsigned short* Xc = (unsigned short*)((char*)d_ws + (size_t)6291456);      // 3 MB
    unsigned short* Wc = (unsigned short*)((char*)d_ws + (size_t)6291456 + 3145728); // 1.125 MB

    split_bf16<<<dim3(M_ROWS + 768), 64, 0, stream>>>(x, Wq, Wk, Wv, Xc, Wc);
    qkv_mfma<<<dim3(384), 64, 0, stream>>>(Xc, Wc, Qh, Kh, Vt);
    attn_fused<<<dim3(512), 512, 0, stream>>>(Qh, Kh, Vt, w_mlp, b_mlp, outp);
}

// Round 10
// 110.305 us; speedup vs baseline: 1.0855x; 1.0855x over previous
//
#include <hip/hip_runtime.h>

typedef float f32x2 __attribute__((ext_vector_type(2)));
typedef float f32x4 __attribute__((ext_vector_type(4)));
typedef _Float16 h16x2 __attribute__((ext_vector_type(2)));
typedef _Float16 h16x4 __attribute__((ext_vector_type(4)));
typedef _Float16 h16x8 __attribute__((ext_vector_type(8)));

#define LL 512
#define M_ROWS 2048            // 4 * 512

#if __has_builtin(__builtin_amdgcn_exp2f)
#define EXP2F __builtin_amdgcn_exp2f
#else
#define EXP2F exp2f
#endif
#define LOG2E 1.44269504088896340736f

__device__ __forceinline__ float quad_swap1(float x) {
    return __int_as_float(__builtin_amdgcn_mov_dpp(__float_as_int(x), 0xB1, 0xF, 0xF, true));
}
__device__ __forceinline__ float quad_swap2(float x) {
    return __int_as_float(__builtin_amdgcn_mov_dpp(__float_as_int(x), 0x4E, 0xF, 0xF, true));
}

__device__ __forceinline__ float fdot2f(h16x2 a, h16x2 b, float c) {
#if __has_builtin(__builtin_amdgcn_fdot2)
    return __builtin_amdgcn_fdot2(a, b, c, false);
#else
    return fmaf((float)a.x, (float)b.x, fmaf((float)a.y, (float)b.y, c));
#endif
}

// ---------------------------------------------------------------------------
// Kernel 1: fp32 VALU GEMM (exact), R2 structure. Y = X @ W.T.
// grid (12, 64): bx = mat(3) x n-tile(4x64); by = 64 m-tiles of 32 rows.
// 128 threads, kc=32 double-buffered LDS, 4x4 micro-tile.
// Epilogue: mat 0/1 -> f16 (Qh/Kh); mat 2 -> f32 Vt. Vt column permutation
// sigma(n) = (n&31)*8 + (n>>5) applied via W-row indexing (verified R2/R8).
// ---------------------------------------------------------------------------
__global__ __launch_bounds__(128) void qkv_gemm(
    const float* __restrict__ X, const float* __restrict__ Wq,
    const float* __restrict__ Wk, const float* __restrict__ Wv,
    _Float16* __restrict__ Qh, _Float16* __restrict__ Kh, float* __restrict__ Vt)
{
    const int bx = blockIdx.x;           // 0..11
    const int by = blockIdx.y;           // 0..63
    const int mat = bx >> 2;
    const int n0 = (bx & 3) * 64;
    const int m0 = by * 32;
    const float* W = (mat == 0) ? Wq : (mat == 1 ? Wk : Wv);

    __shared__ float As[2][32][36];
    __shared__ float Bs[2][32][68];

    const int t = threadIdx.x;
    const int tx = t & 15;               // n micro
    const int ty = t >> 4;               // m micro (0..7)

    int am[2], ak4[2];
#pragma unroll
    for (int r = 0; r < 2; ++r) { int idx = t + 128 * r; am[r] = idx >> 3; ak4[r] = idx & 7; }
    int bn[4], bk4[4]; size_t brow[4];
#pragma unroll
    for (int r = 0; r < 4; ++r) {
        int idx = t + 128 * r; bn[r] = idx >> 3; bk4[r] = idx & 7;
        int rowc = n0 + bn[r];
        brow[r] = (mat == 2) ? (size_t)(((rowc & 31) << 3) | (rowc >> 5)) : (size_t)rowc;
    }

    f32x4 arg[2], brg[4];
    auto load_tile = [&](int kc) {
#pragma unroll
        for (int r = 0; r < 2; ++r)
            arg[r] = *(const f32x4*)(X + (size_t)(m0 + am[r]) * 256 + kc + ak4[r] * 4);
#pragma unroll
        for (int r = 0; r < 4; ++r)
            brg[r] = *(const f32x4*)(W + brow[r] * 256 + kc + bk4[r] * 4);
    };
    auto store_tile = [&](int buf) {
#pragma unroll
        for (int r = 0; r < 2; ++r)
#pragma unroll
            for (int j = 0; j < 4; ++j) As[buf][ak4[r] * 4 + j][am[r]] = arg[r][j];
#pragma unroll
        for (int r = 0; r < 4; ++r)
#pragma unroll
            for (int j = 0; j < 4; ++j) Bs[buf][bk4[r] * 4 + j][bn[r]] = brg[r][j];
    };

    load_tile(0);
    store_tile(0);
    __syncthreads();

    f32x2 c[4][2];
#pragma unroll
    for (int i = 0; i < 4; ++i) { c[i][0] = (f32x2){0.f, 0.f}; c[i][1] = (f32x2){0.f, 0.f}; }

    for (int it = 0; it < 8; ++it) {
        const int buf = it & 1;
        if (it < 7) load_tile((it + 1) * 32);
#pragma unroll
        for (int kk = 0; kk < 32; ++kk) {
            const f32x4 a4 = *(const f32x4*)&As[buf][kk][ty * 4];
            const f32x4 b4 = *(const f32x4*)&Bs[buf][kk][tx * 4];
            const f32x2 bl = __builtin_shufflevector(b4, b4, 0, 1);
            const f32x2 bh = __builtin_shufflevector(b4, b4, 2, 3);
#pragma unroll
            for (int i = 0; i < 4; ++i) {
                const f32x2 ai = {a4[i], a4[i]};
                c[i][0] += ai * bl;
                c[i][1] += ai * bh;
            }
        }
        if (it < 7) {
            __syncthreads();
            store_tile(buf ^ 1);
            __syncthreads();
        }
    }

    const int colb = n0 + tx * 4;
    if (mat == 2) {
#pragma unroll
        for (int i = 0; i < 4; ++i) {
            f32x4 v = {c[i][0].x, c[i][0].y, c[i][1].x, c[i][1].y};
            *(f32x4*)(Vt + (size_t)(m0 + ty * 4 + i) * 256 + colb) = v;
        }
    } else {
        _Float16* Hb = (mat == 0) ? Qh : Kh;
#pragma unroll
        for (int i = 0; i < 4; ++i) {
            h16x4 hv = {(_Float16)c[i][0].x, (_Float16)c[i][0].y,
                        (_Float16)c[i][1].x, (_Float16)c[i][1].y};
            *(h16x4*)(Hb + (size_t)(m0 + ty * 4 + i) * 256 + colb) = hv;
        }
    }
}

// ---------------------------------------------------------------------------
// Kernel 2: fused grouped-MLP attention — R8 verbatim (best measured).
// grid 512 = 4 batches x 128 q-tiles (4 q rows), 512 threads, 2 blocks/CU.
// thread = (dh = t&3: 8 contiguous d's, g = (t>>2)&7, p = t>>5: k-phase 0..15).
// ---------------------------------------------------------------------------
__global__ __launch_bounds__(512, 4) void attn_fused(
    const _Float16* __restrict__ Qh, const _Float16* __restrict__ Kh,
    const float* __restrict__ Vt,
    const float* __restrict__ w_mlp, const float* __restrict__ b_mlp,
    float* __restrict__ out)
{
    const int bid = blockIdx.x;
    const int b = bid & 3;
    const int q0 = (bid >> 2) * 4;

    const int t = threadIdx.x;
    const int dh = t & 3;
    const int p = t >> 5;                    // 0..15
    const int lane32 = t & 31;               // g*4 + dh
    const int g = lane32 >> 2;

    __shared__ float accbuf[16][32][37];     // 75776 B (rows: 4q*8 + l[4])

    const int doff = g * 32 + dh * 8;
    const float bias4 = b_mlp[0] * (LOG2E * 0.25f);

    h16x2 w2[4];
    {
        f32x4 wa = *(const f32x4*)(w_mlp + dh * 8);
        f32x4 wb = *(const f32x4*)(w_mlp + dh * 8 + 4);
        wa *= LOG2E; wb *= LOG2E;
        w2[0] = (h16x2){(_Float16)wa.x, (_Float16)wa.y};
        w2[1] = (h16x2){(_Float16)wa.z, (_Float16)wa.w};
        w2[2] = (h16x2){(_Float16)wb.x, (_Float16)wb.y};
        w2[3] = (h16x2){(_Float16)wb.z, (_Float16)wb.w};
    }

    h16x2 qr2[4][4];
#pragma unroll
    for (int q = 0; q < 4; ++q) {
        const h16x8 qv = *(const h16x8*)(Qh + ((size_t)(b * LL) + q0 + q) * 256 + doff);
        qr2[q][0] = __builtin_shufflevector(qv, qv, 0, 1);
        qr2[q][1] = __builtin_shufflevector(qv, qv, 2, 3);
        qr2[q][2] = __builtin_shufflevector(qv, qv, 4, 5);
        qr2[q][3] = __builtin_shufflevector(qv, qv, 6, 7);
    }

    f32x2 acc2[4][4];
#pragma unroll
    for (int q = 0; q < 4; ++q)
#pragma unroll
        for (int j = 0; j < 4; ++j) acc2[q][j] = (f32x2){0.f, 0.f};
    float l[4] = {0.f, 0.f, 0.f, 0.f};

    const _Float16* kptr = Kh + ((size_t)(b * LL) + p) * 256 + doff;
    const float* vptr = Vt + ((size_t)(b * LL) + p) * 256 + doff;

    const h16x2 zh = {(_Float16)0.f, (_Float16)0.f};

    auto compute = [&](h16x8 kv, f32x4 va, f32x4 vb) {
        h16x2 k2[4] = {__builtin_shufflevector(kv, kv, 0, 1),
                       __builtin_shufflevector(kv, kv, 2, 3),
                       __builtin_shufflevector(kv, kv, 4, 5),
                       __builtin_shufflevector(kv, kv, 6, 7)};
        f32x2 v2[4] = {__builtin_shufflevector(va, va, 0, 1),
                       __builtin_shufflevector(va, va, 2, 3),
                       __builtin_shufflevector(vb, vb, 0, 1),
                       __builtin_shufflevector(vb, vb, 2, 3)};
#pragma unroll
        for (int q = 0; q < 4; ++q) {
            float s = bias4;
#pragma unroll
            for (int j = 0; j < 4; ++j) {
                h16x2 d2 = qr2[q][j] - k2[j];
                h16x2 r2 = __builtin_elementwise_max(d2, zh);
                s = fdot2f(w2[j], r2, s);
            }
            s += quad_swap1(s);
            s += quad_swap2(s);
            s = fmaxf(s, 0.f);
            const float e = EXP2F(s);
            l[q] += e;
            const f32x2 e2 = {e, e};
#pragma unroll
            for (int j = 0; j < 4; ++j)
                acc2[q][j] = __builtin_elementwise_fma(v2[j], e2, acc2[q][j]);
        }
    };

    h16x8 kc = *(const h16x8*)kptr;
    f32x4 va = *(const f32x4*)vptr, vb = *(const f32x4*)(vptr + 4);
#pragma unroll 1
    for (int i = 0; i < 31; ++i) {
        kptr += 16 * 256; vptr += 16 * 256;
        h16x8 kn = *(const h16x8*)kptr;
        f32x4 va2 = *(const f32x4*)vptr, vb2 = *(const f32x4*)(vptr + 4);
        compute(kc, va, vb);
        kc = kn; va = va2; vb = vb2;
    }
    compute(kc, va, vb);

    // ---- epilogue: store 4 q + l, 16-phase LDS reduction, 2 outputs/thread --
    {
        float* rowp = &accbuf[p][lane32][0];
#pragma unroll
        for (int qq = 0; qq < 4; ++qq)
#pragma unroll
            for (int j = 0; j < 4; ++j)
                *(f32x2*)(rowp + qq * 8 + j * 2) = acc2[qq][j];
        if (dh == 0) {
#pragma unroll
            for (int qq = 0; qq < 4; ++qq) accbuf[p][lane32][32 + qq] = l[qq];
        }
    }
    __syncthreads();

    const int c_o = t & 255;
    const int g_o = c_o & 7, d_o = c_o >> 3;
    const int rowb = g_o * 4 + (d_o >> 3);
    const int colb = d_o & 7;
    const int qsel = t >> 8;                 // 0..1
#pragma unroll
    for (int h = 0; h < 2; ++h) {
        const int qh = qsel + 2 * h;         // 0..3
        float s = 0.f, ls = 0.f;
#pragma unroll
        for (int pp = 0; pp < 16; ++pp) {
            s  += accbuf[pp][rowb][qh * 8 + colb];
            ls += accbuf[pp][g_o * 4][32 + qh];
        }
        out[((size_t)(b * LL) + q0 + qh) * 256 + c_o] = s / ls;
    }
}

// ---------------------------------------------------------------------------
extern "C" void kernel_launch(void* const* d_in, const int* in_sizes, int n_in,
                              void* d_out, int out_size, void* d_ws, size_t ws_size,
                              hipStream_t stream) {
    (void)in_sizes; (void)n_in; (void)out_size; (void)ws_size;
    const float* x     = (const float*)d_in[0];
    const float* Wq    = (const float*)d_in[1];
    const float* Wk    = (const float*)d_in[2];
    const float* Wv    = (const float*)d_in[3];
    const float* w_mlp = (const float*)d_in[4];
    const float* b_mlp = (const float*)d_in[5];
    float* outp = (float*)d_out;

    _Float16* Qh = (_Float16*)d_ws;                            // 1 MB
    _Float16* Kh = (_Float16*)((char*)d_ws + (size_t)1048576); // 1 MB
    float*    Vt = (float*)((char*)d_ws + (size_t)2097152);    // 2 MB

    qkv_gemm<<<dim3(12, 64), 128, 0, stream>>>(x, Wq, Wk, Wv, Qh, Kh, Vt);
    attn_fused<<<dim3(512), 512, 0, stream>>>(Qh, Kh, Vt, w_mlp, b_mlp, outp);
}

// Round 11
// 108.967 us; speedup vs baseline: 1.0988x; 1.0123x over previous
//
#include <hip/hip_runtime.h>

typedef float f32x2 __attribute__((ext_vector_type(2)));
typedef float f32x4 __attribute__((ext_vector_type(4)));
typedef _Float16 h16x2 __attribute__((ext_vector_type(2)));
typedef _Float16 h16x4 __attribute__((ext_vector_type(4)));
typedef _Float16 h16x8 __attribute__((ext_vector_type(8)));

#define LL 512
#define M_ROWS 2048            // 4 * 512

#if __has_builtin(__builtin_amdgcn_exp2f)
#define EXP2F __builtin_amdgcn_exp2f
#else
#define EXP2F exp2f
#endif
#define LOG2E 1.44269504088896340736f

__device__ __forceinline__ float quad_swap1(float x) {
    return __int_as_float(__builtin_amdgcn_mov_dpp(__float_as_int(x), 0xB1, 0xF, 0xF, true));
}
__device__ __forceinline__ float quad_swap2(float x) {
    return __int_as_float(__builtin_amdgcn_mov_dpp(__float_as_int(x), 0x4E, 0xF, 0xF, true));
}

__device__ __forceinline__ float fdot2f(h16x2 a, h16x2 b, float c) {
#if __has_builtin(__builtin_amdgcn_fdot2)
    return __builtin_amdgcn_fdot2(a, b, c, false);
#else
    return fmaf((float)a.x, (float)b.x, fmaf((float)a.y, (float)b.y, c));
#endif
}

// ---------------------------------------------------------------------------
// Kernel 1: fp32 VALU GEMM (exact), unchanged from R10.
// Epilogue: mat 0/1 -> f16 (Qh/Kh); mat 2 -> f32 Vt with column permutation
// sigma(n) = (n&31)*8 + (n>>5) via W-row indexing.
// ---------------------------------------------------------------------------
__global__ __launch_bounds__(128) void qkv_gemm(
    const float* __restrict__ X, const float* __restrict__ Wq,
    const float* __restrict__ Wk, const float* __restrict__ Wv,
    _Float16* __restrict__ Qh, _Float16* __restrict__ Kh, float* __restrict__ Vt)
{
    const int bx = blockIdx.x;           // 0..11
    const int by = blockIdx.y;           // 0..63
    const int mat = bx >> 2;
    const int n0 = (bx & 3) * 64;
    const int m0 = by * 32;
    const float* W = (mat == 0) ? Wq : (mat == 1 ? Wk : Wv);

    __shared__ float As[2][32][36];
    __shared__ float Bs[2][32][68];

    const int t = threadIdx.x;
    const int tx = t & 15;               // n micro
    const int ty = t >> 4;               // m micro (0..7)

    int am[2], ak4[2];
#pragma unroll
    for (int r = 0; r < 2; ++r) { int idx = t + 128 * r; am[r] = idx >> 3; ak4[r] = idx & 7; }
    int bn[4], bk4[4]; size_t brow[4];
#pragma unroll
    for (int r = 0; r < 4; ++r) {
        int idx = t + 128 * r; bn[r] = idx >> 3; bk4[r] = idx & 7;
        int rowc = n0 + bn[r];
        brow[r] = (mat == 2) ? (size_t)(((rowc & 31) << 3) | (rowc >> 5)) : (size_t)rowc;
    }

    f32x4 arg[2], brg[4];
    auto load_tile = [&](int kc) {
#pragma unroll
        for (int r = 0; r < 2; ++r)
            arg[r] = *(const f32x4*)(X + (size_t)(m0 + am[r]) * 256 + kc + ak4[r] * 4);
#pragma unroll
        for (int r = 0; r < 4; ++r)
            brg[r] = *(const f32x4*)(W + brow[r] * 256 + kc + bk4[r] * 4);
    };
    auto store_tile = [&](int buf) {
#pragma unroll
        for (int r = 0; r < 2; ++r)
#pragma unroll
            for (int j = 0; j < 4; ++j) As[buf][ak4[r] * 4 + j][am[r]] = arg[r][j];
#pragma unroll
        for (int r = 0; r < 4; ++r)
#pragma unroll
            for (int j = 0; j < 4; ++j) Bs[buf][bk4[r] * 4 + j][bn[r]] = brg[r][j];
    };

    load_tile(0);
    store_tile(0);
    __syncthreads();

    f32x2 c[4][2];
#pragma unroll
    for (int i = 0; i < 4; ++i) { c[i][0] = (f32x2){0.f, 0.f}; c[i][1] = (f32x2){0.f, 0.f}; }

    for (int it = 0; it < 8; ++it) {
        const int buf = it & 1;
        if (it < 7) load_tile((it + 1) * 32);
#pragma unroll
        for (int kk = 0; kk < 32; ++kk) {
            const f32x4 a4 = *(const f32x4*)&As[buf][kk][ty * 4];
            const f32x4 b4 = *(const f32x4*)&Bs[buf][kk][tx * 4];
            const f32x2 bl = __builtin_shufflevector(b4, b4, 0, 1);
            const f32x2 bh = __builtin_shufflevector(b4, b4, 2, 3);
#pragma unroll
            for (int i = 0; i < 4; ++i) {
                const f32x2 ai = {a4[i], a4[i]};
                c[i][0] += ai * bl;
                c[i][1] += ai * bh;
            }
        }
        if (it < 7) {
            __syncthreads();
            store_tile(buf ^ 1);
            __syncthreads();
        }
    }

    const int colb = n0 + tx * 4;
    if (mat == 2) {
#pragma unroll
        for (int i = 0; i < 4; ++i) {
            f32x4 v = {c[i][0].x, c[i][0].y, c[i][1].x, c[i][1].y};
            *(f32x4*)(Vt + (size_t)(m0 + ty * 4 + i) * 256 + colb) = v;
        }
    } else {
        _Float16* Hb = (mat == 0) ? Qh : Kh;
#pragma unroll
        for (int i = 0; i < 4; ++i) {
            h16x4 hv = {(_Float16)c[i][0].x, (_Float16)c[i][0].y,
                        (_Float16)c[i][1].x, (_Float16)c[i][1].y};
            *(h16x4*)(Hb + (size_t)(m0 + ty * 4 + i) * 256 + colb) = hv;
        }
    }
}

// ---------------------------------------------------------------------------
// Kernel 2: fused grouped-MLP attention — f16 score path, exp-deduped quad
// reduction: transpose-reduce gives lane dh the full sum for q==dh (1 exp per
// quad per q instead of 4), then 3 DPP movs broadcast e back. Lane dh's acc
// slot s holds q = dh ^ s; epilogue un-permutes.
// grid 512 = 4 batches x 128 q-tiles (4 q rows), 512 threads, 2 blocks/CU.
// ---------------------------------------------------------------------------
__global__ __launch_bounds__(512, 4) void attn_fused(
    const _Float16* __restrict__ Qh, const _Float16* __restrict__ Kh,
    const float* __restrict__ Vt,
    const float* __restrict__ w_mlp, const float* __restrict__ b_mlp,
    float* __restrict__ out)
{
    const int bid = blockIdx.x;
    const int b = bid & 3;
    const int q0 = (bid >> 2) * 4;

    const int t = threadIdx.x;
    const int dh = t & 3;
    const int p = t >> 5;                    // 0..15
    const int lane32 = t & 31;               // g*4 + dh
    const int g = lane32 >> 2;

    __shared__ float accbuf[16][32][37];     // 75776 B (rows: 4q*8 + l at 32)

    const int doff = g * 32 + dh * 8;
    const float bias4 = b_mlp[0] * (LOG2E * 0.25f);
    const bool odd = (dh & 1) != 0;
    const bool hi  = (dh & 2) != 0;

    h16x2 w2[4];
    {
        f32x4 wa = *(const f32x4*)(w_mlp + dh * 8);
        f32x4 wb = *(const f32x4*)(w_mlp + dh * 8 + 4);
        wa *= LOG2E; wb *= LOG2E;
        w2[0] = (h16x2){(_Float16)wa.x, (_Float16)wa.y};
        w2[1] = (h16x2){(_Float16)wa.z, (_Float16)wa.w};
        w2[2] = (h16x2){(_Float16)wb.x, (_Float16)wb.y};
        w2[3] = (h16x2){(_Float16)wb.z, (_Float16)wb.w};
    }

    h16x2 qr2[4][4];
#pragma unroll
    for (int q = 0; q < 4; ++q) {
        const h16x8 qv = *(const h16x8*)(Qh + ((size_t)(b * LL) + q0 + q) * 256 + doff);
        qr2[q][0] = __builtin_shufflevector(qv, qv, 0, 1);
        qr2[q][1] = __builtin_shufflevector(qv, qv, 2, 3);
        qr2[q][2] = __builtin_shufflevector(qv, qv, 4, 5);
        qr2[q][3] = __builtin_shufflevector(qv, qv, 6, 7);
    }

    f32x2 acc2[4][4];                        // slot s <-> q = dh ^ s
#pragma unroll
    for (int s = 0; s < 4; ++s)
#pragma unroll
        for (int j = 0; j < 4; ++j) acc2[s][j] = (f32x2){0.f, 0.f};
    float lown = 0.f;                        // l for q == dh

    const _Float16* kptr = Kh + ((size_t)(b * LL) + p) * 256 + doff;
    const float* vptr = Vt + ((size_t)(b * LL) + p) * 256 + doff;

    const h16x2 zh = {(_Float16)0.f, (_Float16)0.f};

    auto compute = [&](h16x8 kv, f32x4 va, f32x4 vb) {
        h16x2 k2[4] = {__builtin_shufflevector(kv, kv, 0, 1),
                       __builtin_shufflevector(kv, kv, 2, 3),
                       __builtin_shufflevector(kv, kv, 4, 5),
                       __builtin_shufflevector(kv, kv, 6, 7)};
        f32x2 v2[4] = {__builtin_shufflevector(va, va, 0, 1),
                       __builtin_shufflevector(va, va, 2, 3),
                       __builtin_shufflevector(vb, vb, 0, 1),
                       __builtin_shufflevector(vb, vb, 2, 3)};
        // partial scores (this lane's 8 d's) for all 4 q
        float ps[4];
#pragma unroll
        for (int q = 0; q < 4; ++q) {
            float s = bias4;
#pragma unroll
            for (int j = 0; j < 4; ++j) {
                h16x2 d2 = qr2[q][j] - k2[j];
                h16x2 r2 = __builtin_elementwise_max(d2, zh);
                s = fdot2f(w2[j], r2, s);
            }
            ps[q] = s;
        }
        // quad transpose-reduce: lane dh ends with full sum for q == dh
        const float r01 = quad_swap1(odd ? ps[0] : ps[1]);
        const float z01 = (odd ? ps[1] : ps[0]) + r01;
        const float r23 = quad_swap1(odd ? ps[2] : ps[3]);
        const float z23 = (odd ? ps[3] : ps[2]) + r23;
        const float r2f = quad_swap2(hi ? z01 : z23);
        const float zz  = (hi ? z23 : z01) + r2f;
        const float sfull = fmaxf(zz, 0.f);
        const float e = EXP2F(sfull);        // one exp per (quad, q)
        lown += e;
        // broadcast: slot s gets e for q = dh ^ s
        const float e1 = quad_swap1(e);
        const float e2 = quad_swap2(e);
        const float e3 = quad_swap2(e1);
        const float es[4] = {e, e1, e2, e3};
#pragma unroll
        for (int s = 0; s < 4; ++s) {
            const f32x2 ee = {es[s], es[s]};
#pragma unroll
            for (int j = 0; j < 4; ++j)
                acc2[s][j] = __builtin_elementwise_fma(v2[j], ee, acc2[s][j]);
        }
    };

    h16x8 kc = *(const h16x8*)kptr;
    f32x4 va = *(const f32x4*)vptr, vb = *(const f32x4*)(vptr + 4);
#pragma unroll 1
    for (int i = 0; i < 31; ++i) {
        kptr += 16 * 256; vptr += 16 * 256;
        h16x8 kn = *(const h16x8*)kptr;
        f32x4 va2 = *(const f32x4*)vptr, vb2 = *(const f32x4*)(vptr + 4);
        compute(kc, va, vb);
        kc = kn; va = va2; vb = vb2;
    }
    compute(kc, va, vb);

    // ---- epilogue: un-permute slots (q = dh ^ s), 16-phase LDS reduction ----
    {
        float* rowp = &accbuf[p][lane32][0];
#pragma unroll
        for (int s = 0; s < 4; ++s) {
            const int qq = dh ^ s;
#pragma unroll
            for (int j = 0; j < 4; ++j)
                *(f32x2*)(rowp + qq * 8 + j * 2) = acc2[s][j];
        }
        accbuf[p][lane32][32] = lown;        // l for q == dh, every lane
    }
    __syncthreads();

    const int c_o = t & 255;
    const int g_o = c_o & 7, d_o = c_o >> 3;
    const int rowb = g_o * 4 + (d_o >> 3);
    const int colb = d_o & 7;
    const int qsel = t >> 8;                 // 0..1
#pragma unroll
    for (int h = 0; h < 2; ++h) {
        const int qh = qsel + 2 * h;         // 0..3
        float s = 0.f, ls = 0.f;
#pragma unroll
        for (int pp = 0; pp < 16; ++pp) {
            s  += accbuf[pp][rowb][qh * 8 + colb];
            ls += accbuf[pp][g_o * 4 + qh][32];
        }
        out[((size_t)(b * LL) + q0 + qh) * 256 + c_o] = s / ls;
    }
}

// ---------------------------------------------------------------------------
extern "C" void kernel_launch(void* const* d_in, const int* in_sizes, int n_in,
                              void* d_out, int out_size, void* d_ws, size_t ws_size,
                              hipStream_t stream) {
    (void)in_sizes; (void)n_in; (void)out_size; (void)ws_size;
    const float* x     = (const float*)d_in[0];
    const float* Wq    = (const float*)d_in[1];
    const float* Wk    = (const float*)d_in[2];
    const float* Wv    = (const float*)d_in[3];
    const float* w_mlp = (const float*)d_in[4];
    const float* b_mlp = (const float*)d_in[5];
    float* outp = (float*)d_out;

    _Float16* Qh = (_Float16*)d_ws;                            // 1 MB
    _Float16* Kh = (_Float16*)((char*)d_ws + (size_t)1048576); // 1 MB
    float*    Vt = (float*)((char*)d_ws + (size_t)2097152);    // 2 MB

    qkv_gemm<<<dim3(12, 64), 128, 0, stream>>>(x, Wq, Wk, Wv, Qh, Kh, Vt);
    attn_fused<<<dim3(512), 512, 0, stream>>>(Qh, Kh, Vt, w_mlp, b_mlp, outp);
}

// Round 12
// 108.896 us; speedup vs baseline: 1.0995x; 1.0007x over previous
//
#include <hip/hip_runtime.h>

typedef float f32x2 __attribute__((ext_vector_type(2)));
typedef float f32x4 __attribute__((ext_vector_type(4)));
typedef _Float16 h16x2 __attribute__((ext_vector_type(2)));
typedef _Float16 h16x4 __attribute__((ext_vector_type(4)));
typedef _Float16 h16x8 __attribute__((ext_vector_type(8)));

#define LL 512
#define M_ROWS 2048            // 4 * 512

#if __has_builtin(__builtin_amdgcn_exp2f)
#define EXP2F __builtin_amdgcn_exp2f
#else
#define EXP2F exp2f
#endif
#define LOG2E 1.44269504088896340736f

__device__ __forceinline__ float quad_swap1(float x) {
    return __int_as_float(__builtin_amdgcn_mov_dpp(__float_as_int(x), 0xB1, 0xF, 0xF, true));
}
__device__ __forceinline__ float quad_swap2(float x) {
    return __int_as_float(__builtin_amdgcn_mov_dpp(__float_as_int(x), 0x4E, 0xF, 0xF, true));
}

__device__ __forceinline__ float fdot2f(h16x2 a, h16x2 b, float c) {
#if __has_builtin(__builtin_amdgcn_fdot2)
    return __builtin_amdgcn_fdot2(a, b, c, false);
#else
    return fmaf((float)a.x, (float)b.x, fmaf((float)a.y, (float)b.y, c));
#endif
}

// ---------------------------------------------------------------------------
// Kernel 1: fp32 VALU GEMM (exact), unchanged from R10/R11.
// LDS-BW-bound at ~10-11 us (r = 1 B/FLOP with 4x4 micro-tile) — at floor
// for this grid/occupancy tradeoff.
// ---------------------------------------------------------------------------
__global__ __launch_bounds__(128) void qkv_gemm(
    const float* __restrict__ X, const float* __restrict__ Wq,
    const float* __restrict__ Wk, const float* __restrict__ Wv,
    _Float16* __restrict__ Qh, _Float16* __restrict__ Kh, float* __restrict__ Vt)
{
    const int bx = blockIdx.x;           // 0..11
    const int by = blockIdx.y;           // 0..63
    const int mat = bx >> 2;
    const int n0 = (bx & 3) * 64;
    const int m0 = by * 32;
    const float* W = (mat == 0) ? Wq : (mat == 1 ? Wk : Wv);

    __shared__ float As[2][32][36];
    __shared__ float Bs[2][32][68];

    const int t = threadIdx.x;
    const int tx = t & 15;               // n micro
    const int ty = t >> 4;               // m micro (0..7)

    int am[2], ak4[2];
#pragma unroll
    for (int r = 0; r < 2; ++r) { int idx = t + 128 * r; am[r] = idx >> 3; ak4[r] = idx & 7; }
    int bn[4], bk4[4]; size_t brow[4];
#pragma unroll
    for (int r = 0; r < 4; ++r) {
        int idx = t + 128 * r; bn[r] = idx >> 3; bk4[r] = idx & 7;
        int rowc = n0 + bn[r];
        brow[r] = (mat == 2) ? (size_t)(((rowc & 31) << 3) | (rowc >> 5)) : (size_t)rowc;
    }

    f32x4 arg[2], brg[4];
    auto load_tile = [&](int kc) {
#pragma unroll
        for (int r = 0; r < 2; ++r)
            arg[r] = *(const f32x4*)(X + (size_t)(m0 + am[r]) * 256 + kc + ak4[r] * 4);
#pragma unroll
        for (int r = 0; r < 4; ++r)
            brg[r] = *(const f32x4*)(W + brow[r] * 256 + kc + bk4[r] * 4);
    };
    auto store_tile = [&](int buf) {
#pragma unroll
        for (int r = 0; r < 2; ++r)
#pragma unroll
            for (int j = 0; j < 4; ++j) As[buf][ak4[r] * 4 + j][am[r]] = arg[r][j];
#pragma unroll
        for (int r = 0; r < 4; ++r)
#pragma unroll
            for (int j = 0; j < 4; ++j) Bs[buf][bk4[r] * 4 + j][bn[r]] = brg[r][j];
    };

    load_tile(0);
    store_tile(0);
    __syncthreads();

    f32x2 c[4][2];
#pragma unroll
    for (int i = 0; i < 4; ++i) { c[i][0] = (f32x2){0.f, 0.f}; c[i][1] = (f32x2){0.f, 0.f}; }

    for (int it = 0; it < 8; ++it) {
        const int buf = it & 1;
        if (it < 7) load_tile((it + 1) * 32);
#pragma unroll
        for (int kk = 0; kk < 32; ++kk) {
            const f32x4 a4 = *(const f32x4*)&As[buf][kk][ty * 4];
            const f32x4 b4 = *(const f32x4*)&Bs[buf][kk][tx * 4];
            const f32x2 bl = __builtin_shufflevector(b4, b4, 0, 1);
            const f32x2 bh = __builtin_shufflevector(b4, b4, 2, 3);
#pragma unroll
            for (int i = 0; i < 4; ++i) {
                const f32x2 ai = {a4[i], a4[i]};
                c[i][0] += ai * bl;
                c[i][1] += ai * bh;
            }
        }
        if (it < 7) {
            __syncthreads();
            store_tile(buf ^ 1);
            __syncthreads();
        }
    }

    const int colb = n0 + tx * 4;
    if (mat == 2) {
#pragma unroll
        for (int i = 0; i < 4; ++i) {
            f32x4 v = {c[i][0].x, c[i][0].y, c[i][1].x, c[i][1].y};
            *(f32x4*)(Vt + (size_t)(m0 + ty * 4 + i) * 256 + colb) = v;
        }
    } else {
        _Float16* Hb = (mat == 0) ? Qh : Kh;
#pragma unroll
        for (int i = 0; i < 4; ++i) {
            h16x4 hv = {(_Float16)c[i][0].x, (_Float16)c[i][0].y,
                        (_Float16)c[i][1].x, (_Float16)c[i][1].y};
            *(h16x4*)(Hb + (size_t)(m0 + ty * 4 + i) * 256 + colb) = hv;
        }
    }
}

// ---------------------------------------------------------------------------
// Kernel 2: fused grouped-MLP attention — R11 body (f16 score, exp-deduped
// quad transpose-reduce), epilogue split into 2 rounds of 2 q:
// LDS 38,912 B -> 4 blocks/CU (8 waves/SIMD) for chain-stall coverage.
// grid 512 = 4 batches x 128 q-tiles (4 q rows), 512 threads.
// ---------------------------------------------------------------------------
__global__ __launch_bounds__(512, 4) void attn_fused(
    const _Float16* __restrict__ Qh, const _Float16* __restrict__ Kh,
    const float* __restrict__ Vt,
    const float* __restrict__ w_mlp, const float* __restrict__ b_mlp,
    float* __restrict__ out)
{
    const int bid = blockIdx.x;
    const int b = bid & 3;
    const int q0 = (bid >> 2) * 4;

    const int t = threadIdx.x;
    const int dh = t & 3;
    const int p = t >> 5;                    // 0..15
    const int lane32 = t & 31;               // g*4 + dh
    const int g = lane32 >> 2;

    __shared__ float accbuf[16][32][19];     // 38,912 B (2q x 8 + l[2] + pad)

    const int doff = g * 32 + dh * 8;
    const float bias4 = b_mlp[0] * (LOG2E * 0.25f);
    const bool odd = (dh & 1) != 0;
    const bool hi  = (dh & 2) != 0;

    h16x2 w2[4];
    {
        f32x4 wa = *(const f32x4*)(w_mlp + dh * 8);
        f32x4 wb = *(const f32x4*)(w_mlp + dh * 8 + 4);
        wa *= LOG2E; wb *= LOG2E;
        w2[0] = (h16x2){(_Float16)wa.x, (_Float16)wa.y};
        w2[1] = (h16x2){(_Float16)wa.z, (_Float16)wa.w};
        w2[2] = (h16x2){(_Float16)wb.x, (_Float16)wb.y};
        w2[3] = (h16x2){(_Float16)wb.z, (_Float16)wb.w};
    }

    h16x2 qr2[4][4];
#pragma unroll
    for (int q = 0; q < 4; ++q) {
        const h16x8 qv = *(const h16x8*)(Qh + ((size_t)(b * LL) + q0 + q) * 256 + doff);
        qr2[q][0] = __builtin_shufflevector(qv, qv, 0, 1);
        qr2[q][1] = __builtin_shufflevector(qv, qv, 2, 3);
        qr2[q][2] = __builtin_shufflevector(qv, qv, 4, 5);
        qr2[q][3] = __builtin_shufflevector(qv, qv, 6, 7);
    }

    f32x2 acc2[4][4];                        // slot s <-> q = dh ^ s
#pragma unroll
    for (int s = 0; s < 4; ++s)
#pragma unroll
        for (int j = 0; j < 4; ++j) acc2[s][j] = (f32x2){0.f, 0.f};
    float lown = 0.f;                        // l for q == dh

    const _Float16* kptr = Kh + ((size_t)(b * LL) + p) * 256 + doff;
    const float* vptr = Vt + ((size_t)(b * LL) + p) * 256 + doff;

    const h16x2 zh = {(_Float16)0.f, (_Float16)0.f};

    auto compute = [&](h16x8 kv, f32x4 va, f32x4 vb) {
        h16x2 k2[4] = {__builtin_shufflevector(kv, kv, 0, 1),
                       __builtin_shufflevector(kv, kv, 2, 3),
                       __builtin_shufflevector(kv, kv, 4, 5),
                       __builtin_shufflevector(kv, kv, 6, 7)};
        f32x2 v2[4] = {__builtin_shufflevector(va, va, 0, 1),
                       __builtin_shufflevector(va, va, 2, 3),
                       __builtin_shufflevector(vb, vb, 0, 1),
                       __builtin_shufflevector(vb, vb, 2, 3)};
        float ps[4];
#pragma unroll
        for (int q = 0; q < 4; ++q) {
            float s = bias4;
#pragma unroll
            for (int j = 0; j < 4; ++j) {
                h16x2 d2 = qr2[q][j] - k2[j];
                h16x2 r2 = __builtin_elementwise_max(d2, zh);
                s = fdot2f(w2[j], r2, s);
            }
            ps[q] = s;
        }
        // quad transpose-reduce: lane dh ends with full sum for q == dh
        const float r01 = quad_swap1(odd ? ps[0] : ps[1]);
        const float z01 = (odd ? ps[1] : ps[0]) + r01;
        const float r23 = quad_swap1(odd ? ps[2] : ps[3]);
        const float z23 = (odd ? ps[3] : ps[2]) + r23;
        const float r2f = quad_swap2(hi ? z01 : z23);
        const float zz  = (hi ? z23 : z01) + r2f;
        const float sfull = fmaxf(zz, 0.f);
        const float e = EXP2F(sfull);        // one exp per (quad, q)
        lown += e;
        const float e1 = quad_swap1(e);
        const float e2 = quad_swap2(e);
        const float e3 = quad_swap2(e1);
        const float es[4] = {e, e1, e2, e3};
#pragma unroll
        for (int s = 0; s < 4; ++s) {
            const f32x2 ee = {es[s], es[s]};
#pragma unroll
            for (int j = 0; j < 4; ++j)
                acc2[s][j] = __builtin_elementwise_fma(v2[j], ee, acc2[s][j]);
        }
    };

    h16x8 kc = *(const h16x8*)kptr;
    f32x4 va = *(const f32x4*)vptr, vb = *(const f32x4*)(vptr + 4);
#pragma unroll 1
    for (int i = 0; i < 31; ++i) {
        kptr += 16 * 256; vptr += 16 * 256;
        h16x8 kn = *(const h16x8*)kptr;
        f32x4 va2 = *(const f32x4*)vptr, vb2 = *(const f32x4*)(vptr + 4);
        compute(kc, va, vb);
        kc = kn; va = va2; vb = vb2;
    }
    compute(kc, va, vb);

    // ---- epilogue: 2 rounds of 2 q; lane's slot s holds q = dh ^ s ----
    const int c_o = t & 255;
    const int g_o = c_o & 7, d_o = c_o >> 3;
    const int rowb = g_o * 4 + (d_o >> 3);
    const int colb = d_o & 7;
    const int qh2 = t >> 8;                  // 0..1

#pragma unroll
    for (int r = 0; r < 2; ++r) {
        if (r) __syncthreads();              // previous round's reads done
        {
            float* rowp = &accbuf[p][lane32][0];
#pragma unroll
            for (int s = 0; s < 4; ++s) {
                const int qq = dh ^ s;
                if ((qq >> 1) == r) {
#pragma unroll
                    for (int j = 0; j < 4; ++j)
                        *(f32x2*)(rowp + (qq & 1) * 8 + j * 2) = acc2[s][j];
                }
            }
            if ((dh >> 1) == r) rowp[16 + (dh & 1)] = lown;
        }
        __syncthreads();
        {
            const int q = 2 * r + qh2;
            float s = 0.f, ls = 0.f;
#pragma unroll
            for (int pp = 0; pp < 16; ++pp) {
                s  += accbuf[pp][rowb][qh2 * 8 + colb];
                ls += accbuf[pp][g_o * 4 + q][16 + qh2];
            }
            out[((size_t)(b * LL) + q0 + q) * 256 + c_o] = s / ls;
        }
    }
}

// ---------------------------------------------------------------------------
extern "C" void kernel_launch(void* const* d_in, const int* in_sizes, int n_in,
                              void* d_out, int out_size, void* d_ws, size_t ws_size,
                              hipStream_t stream) {
    (void)in_sizes; (void)n_in; (void)out_size; (void)ws_size;
    const float* x     = (const float*)d_in[0];
    const float* Wq    = (const float*)d_in[1];
    const float* Wk    = (const float*)d_in[2];
    const float* Wv    = (const float*)d_in[3];
    const float* w_mlp = (const float*)d_in[4];
    const float* b_mlp = (const float*)d_in[5];
    float* outp = (float*)d_out;

    _Float16* Qh = (_Float16*)d_ws;                            // 1 MB
    _Float16* Kh = (_Float16*)((char*)d_ws + (size_t)1048576); // 1 MB
    float*    Vt = (float*)((char*)d_ws + (size_t)2097152);    // 2 MB

    qkv_gemm<<<dim3(12, 64), 128, 0, stream>>>(x, Wq, Wk, Wv, Qh, Kh, Vt);
    attn_fused<<<dim3(512), 512, 0, stream>>>(Qh, Kh, Vt, w_mlp, b_mlp, outp);
}